// Round 1
// baseline (6075.378 us; speedup 1.0000x reference)
//
#include <hip/hip_runtime.h>

#define B 256
#define T 2048
#define HDIM 128
#define G4 512

typedef _Float16 f16;
typedef _Float16 h2 __attribute__((ext_vector_type(2)));

__device__ __forceinline__ float dot2(h2 a, h2 b, float c) {
#if __has_builtin(__builtin_amdgcn_fdot2)
    return __builtin_amdgcn_fdot2(a, b, c, false);
#else
    return c + (float)a[0] * (float)b[0] + (float)a[1] * (float)b[1];
#endif
}

__device__ __forceinline__ float sigm(float x) { return 1.0f / (1.0f + __expf(-x)); }
__device__ __forceinline__ float tanh_(float x) {
    float e = __expf(-2.0f * fabsf(x));
    float t = (1.0f - e) / (1.0f + e);
    return copysignf(t, x);
}

__device__ __forceinline__ void bar() {
    // LDS-only barrier: order ds ops but do NOT drain vmcnt (keeps x-prefetch
    // loads and y-stores in flight across the barrier -- per-step latency win).
    asm volatile("s_waitcnt lgkmcnt(0)" ::: "memory");
    __builtin_amdgcn_s_barrier();
}

// ---------------- fc1: scent[B,T,3] -> x1[T,B,32] f16 (24 real + 8 zero pad) ---------
__global__ __launch_bounds__(256) void fc1_kernel(
    const float* __restrict__ scent,
    const float* __restrict__ W1, const float* __restrict__ b1,
    const float* __restrict__ W2, const float* __restrict__ b2,
    f16* __restrict__ x1) {
    int r = blockIdx.x * 256 + threadIdx.x;   // r = b*T + t
    int b = r >> 11, t = r & 2047;
    float s0 = scent[r * 3], s1 = scent[r * 3 + 1], s2 = scent[r * 3 + 2];
    float a[12];
#pragma unroll
    for (int i = 0; i < 12; i++) {
        float v = W1[i * 3] * s0 + W1[i * 3 + 1] * s1 + W1[i * 3 + 2] * s2 + b1[i];
        a[i] = fmaxf(v, 0.f);
    }
    union { f16 o[32]; uint4 u[4]; } U;
#pragma unroll
    for (int j = 0; j < 24; j++) {
        float v = b2[j];
#pragma unroll
        for (int i = 0; i < 12; i++) v = fmaf(W2[j * 12 + i], a[i], v);
        U.o[j] = (f16)fmaxf(v, 0.f);
    }
#pragma unroll
    for (int j = 24; j < 32; j++) U.o[j] = (f16)0.f;
    uint4* d4 = (uint4*)(x1 + ((size_t)t * B + b) * 32);
#pragma unroll
    for (int i = 0; i < 4; i++) d4[i] = U.u[i];
}

// ---------------- pack Wf1 f32 -> half2 ----------------
__global__ __launch_bounds__(256) void pack_kernel(const float* __restrict__ w,
                                                   unsigned int* __restrict__ o) {
    int i = blockIdx.x * 256 + threadIdx.x;
    if (i < 4096) {
        union { h2 h; unsigned int u; } U;
        U.h[0] = (f16)w[2 * i];
        U.h[1] = (f16)w[2 * i + 1];
        o[i] = U.u;
    }
}

// ---------------- fused LSTM layer: one block per batch row ----------------
// KIN: padded input width (32 or 128); KREAL: real input width (24 or 128);
// KS = (KIN+128)/8 : per-lane k-slice.
template <int KIN, int KREAL, int KS>
__global__ __launch_bounds__(512, 2) void lstm_kernel(
    const f16* __restrict__ x,       // [T,B,KIN] f16
    const float* __restrict__ Wih,   // [512,KREAL]
    const float* __restrict__ Whh,   // [512,128]
    const float* __restrict__ bih, const float* __restrict__ bhh,
    f16* __restrict__ y,             // [T,B,128] f16 (may alias x for in-place)
    float* __restrict__ hT, float* __restrict__ cT) {  // [B,128] each
    constexpr int KTOT = KIN + HDIM;
    static_assert(KS * 8 == KTOT, "slice");
    __shared__ __align__(16) f16 kvec[KTOT];   // [x_t | h_{t-1}] f16
    __shared__ float gbuf[G4];

    const int tid = threadIdx.x;
    const int bb = blockIdx.x;
    const int s = tid & 7;          // k-slice index within gate group
    const int grp = tid >> 3;       // gate group (8 gates each)

    // ---- per-thread weights (f16 packed), gates grp*8+i, k in [s*KS, s*KS+KS) ----
    h2 wh[8][KS / 2];
#pragma unroll
    for (int i = 0; i < 8; i++) {
        int g = grp * 8 + i;
#pragma unroll
        for (int kk = 0; kk < KS / 2; kk++) {
            int k0 = s * KS + 2 * kk;
            int k1 = k0 + 1;
            float w0, w1;
            if (k0 < KIN) w0 = (k0 < KREAL) ? Wih[g * KREAL + k0] : 0.f;
            else          w0 = Whh[g * HDIM + (k0 - KIN)];
            if (k1 < KIN) w1 = (k1 < KREAL) ? Wih[g * KREAL + k1] : 0.f;
            else          w1 = Whh[g * HDIM + (k1 - KIN)];
            h2 p; p[0] = (f16)w0; p[1] = (f16)w1;
            wh[i][kk] = p;
        }
    }
    const float bsum = bih[tid] + bhh[tid];
    float c = 0.f;

    // ---- x stagers: one dword (2 f16) each; dedicated lanes in wave 2+ ----
    constexpr int KIN2 = KIN / 2;
    const bool stager = (tid >= 128) && (tid < 128 + KIN2);
    const int sid = tid - 128;
    const unsigned int* xg = (const unsigned int*)x;

    if (tid < HDIM) kvec[KIN + tid] = (f16)0.f;   // h0 = 0
    if (stager) {
        unsigned int x0 = xg[(size_t)(0 * B + bb) * KIN2 + sid];
        ((unsigned int*)kvec)[sid] = x0;          // x_0 (compiler waits vmcnt)
    }
    unsigned int xr1 = 0, xr2 = 0;                // prefetch pipeline: rows t+1, t+2
    if (stager) {
        xr1 = xg[(size_t)(1 * B + bb) * KIN2 + sid];
        int t2 = (2 < T) ? 2 : T - 1;
        xr2 = xg[(size_t)(t2 * B + bb) * KIN2 + sid];
    }
    __syncthreads();

    for (int t = 0; t < T; t++) {
        // issue prefetch for row t+3 early (hidden under dot compute)
        unsigned int xr3 = 0;
        if (stager) {
            int tn = (t + 3 < T) ? t + 3 : T - 1;
            xr3 = xg[(size_t)tn * B * KIN2 + (size_t)bb * KIN2 + sid];
        }

        // ---- slice read: KS f16 from kvec ----
        union { uint2 u[KS / 4]; h2 h[KS / 2]; } S;
        {
            const uint2* kp = (const uint2*)(kvec + s * KS);
#pragma unroll
            for (int i2 = 0; i2 < KS / 4; i2++) S.u[i2] = kp[i2];
        }

        // ---- partial dots: 8 gates x KS ----
        float acc[8];
#pragma unroll
        for (int i = 0; i < 8; i++) acc[i] = 0.f;
#pragma unroll
        for (int kk = 0; kk < KS / 2; kk++) {
#pragma unroll
            for (int i = 0; i < 8; i++) acc[i] = dot2(wh[i][kk], S.h[kk], acc[i]);
        }

        // ---- split-tree reduce over the 8 sub-lanes; lane s ends with gate grp*8+s = tid ----
        const int h4 = s & 4, h2b = s & 2, h1 = s & 1;
        float q0 = (h4 ? acc[4] : acc[0]) + __shfl_xor(h4 ? acc[0] : acc[4], 4);
        float q1 = (h4 ? acc[5] : acc[1]) + __shfl_xor(h4 ? acc[1] : acc[5], 4);
        float q2 = (h4 ? acc[6] : acc[2]) + __shfl_xor(h4 ? acc[2] : acc[6], 4);
        float q3 = (h4 ? acc[7] : acc[3]) + __shfl_xor(h4 ? acc[3] : acc[7], 4);
        float r0 = (h2b ? q2 : q0) + __shfl_xor(h2b ? q0 : q2, 2);
        float r1 = (h2b ? q3 : q1) + __shfl_xor(h2b ? q1 : q3, 2);
        float v  = (h1 ? r1 : r0) + __shfl_xor(h1 ? r0 : r1, 1);
        v += bsum;

        // ---- activation (wave-uniform gate type: tid>>7; 2=g -> tanh) ----
        const int gt = tid >> 7;
        float act = (gt == 2) ? tanh_(v) : sigm(v);
        gbuf[tid] = act;
        bar();

        // ---- c/h update (threads 0..127) ----
        if (tid < HDIM) {
            float gi = gbuf[tid], gf = gbuf[128 + tid], gg = gbuf[256 + tid], go = gbuf[384 + tid];
            c = gf * c + gi * gg;
            float hh = go * tanh_(c);
            kvec[KIN + tid] = (f16)hh;
            y[((size_t)t * B + bb) * HDIM + tid] = (f16)hh;
            if (t == T - 1) { hT[bb * HDIM + tid] = hh; cT[bb * HDIM + tid] = c; }
        }
        if (stager) {
            ((unsigned int*)kvec)[sid] = xr1;   // x_{t+1}
        }
        xr1 = xr2; xr2 = xr3;
        bar();
    }
}

// ---------------- fc2: y[T,B,128] f16 -> out[B,T,32] f32 ----------------
__global__ __launch_bounds__(256) void fc2_kernel(
    const f16* __restrict__ yin,
    const unsigned int* __restrict__ w1,  // [64][64] half2-packed Wf1
    const float* __restrict__ bf1,
    const float* __restrict__ Wf2,        // [32][64] f32
    const float* __restrict__ bf2,
    float* __restrict__ out) {
    int r = blockIdx.x * 256 + threadIdx.x;   // r = t*B + b
    union { uint4 u4[16]; h2 h[64]; } Y;
    {
        const uint4* yr4 = (const uint4*)(yin + (size_t)r * 128);
#pragma unroll
        for (int i = 0; i < 16; i++) Y.u4[i] = yr4[i];
    }
    float acc2[32];
#pragma unroll
    for (int i = 0; i < 32; i++) acc2[i] = 0.f;

    for (int cO = 0; cO < 64; cO++) {   // rolled: z1[cO] consumed immediately
        float a0 = bf1[cO], a1 = 0.f, a2 = 0.f, a3 = 0.f;
#pragma unroll
        for (int kk = 0; kk < 64; kk += 4) {
            union { unsigned int u; h2 h; } W0, W1x, W2x, W3;
            W0.u = w1[cO * 64 + kk];     a0 = dot2(W0.h,  Y.h[kk],     a0);
            W1x.u = w1[cO * 64 + kk + 1]; a1 = dot2(W1x.h, Y.h[kk + 1], a1);
            W2x.u = w1[cO * 64 + kk + 2]; a2 = dot2(W2x.h, Y.h[kk + 2], a2);
            W3.u = w1[cO * 64 + kk + 3]; a3 = dot2(W3.h,  Y.h[kk + 3], a3);
        }
        float a = fmaxf((a0 + a1) + (a2 + a3), 0.f);
#pragma unroll
        for (int c2 = 0; c2 < 32; c2++) acc2[c2] = fmaf(a, Wf2[c2 * 64 + cO], acc2[c2]);
    }
    float* orow = out + ((size_t)(r & 255) * T + (r >> 8)) * 32;
#pragma unroll
    for (int c2 = 0; c2 < 32; c2++) orow[c2] = fmaxf(acc2[c2] + bf2[c2], 0.f);
}

// ---------------- launch ----------------
extern "C" void kernel_launch(void* const* d_in, const int* in_sizes, int n_in,
                              void* d_out, int out_size, void* d_ws, size_t ws_size,
                              hipStream_t stream) {
    const float* scent = (const float*)d_in[0];
    const float* W1 = (const float*)d_in[1];
    const float* b1 = (const float*)d_in[2];
    const float* W2 = (const float*)d_in[3];
    const float* b2 = (const float*)d_in[4];
    const float* Wih[3] = {(const float*)d_in[5], (const float*)d_in[9], (const float*)d_in[13]};
    const float* Whh[3] = {(const float*)d_in[6], (const float*)d_in[10], (const float*)d_in[14]};
    const float* bihp[3] = {(const float*)d_in[7], (const float*)d_in[11], (const float*)d_in[15]};
    const float* bhhp[3] = {(const float*)d_in[8], (const float*)d_in[12], (const float*)d_in[16]};
    const float* Wf1 = (const float*)d_in[17];
    const float* bf1 = (const float*)d_in[18];
    const float* Wf2 = (const float*)d_in[19];
    const float* bf2 = (const float*)d_in[20];

    const size_t o_x1 = 0;
    const size_t o_y  = 33554432;               // T*B*32*2
    const size_t o_w1 = o_y + 134217728;        // T*B*128*2
    const size_t need = o_w1 + 16384;
    if (ws_size < need) return;

    char* ws = (char*)d_ws;
    f16* x1 = (f16*)(ws + o_x1);                // [T,B,32]
    f16* yb = (f16*)(ws + o_y);                 // [T,B,128], reused in-place per layer
    unsigned int* w1p = (unsigned int*)(ws + o_w1);

    float* out = (float*)d_out;
    float* hO = out + (size_t)B * T * 32;
    float* cO = hO + 3 * B * HDIM;

    pack_kernel<<<16, 256, 0, stream>>>(Wf1, w1p);
    fc1_kernel<<<(B * T) / 256, 256, 0, stream>>>(scent, W1, b1, W2, b2, x1);
    lstm_kernel<32, 24, 20><<<B, 512, 0, stream>>>(x1, Wih[0], Whh[0], bihp[0], bhhp[0],
                                                   yb, hO, cO);
    lstm_kernel<128, 128, 32><<<B, 512, 0, stream>>>(yb, Wih[1], Whh[1], bihp[1], bhhp[1],
                                                     yb, hO + B * HDIM, cO + B * HDIM);
    lstm_kernel<128, 128, 32><<<B, 512, 0, stream>>>(yb, Wih[2], Whh[2], bihp[2], bhhp[2],
                                                     yb, hO + 2 * B * HDIM, cO + 2 * B * HDIM);
    fc2_kernel<<<(B * T) / 256, 256, 0, stream>>>(yb, w1p, bf1, Wf2, bf2, out);
}